// Round 14
// baseline (241.063 us; speedup 1.0000x reference)
//
#include <hip/hip_runtime.h>
#include <stdint.h>

// ---------------------------------------------------------------------------
// HistoryEmbTable: emb.at[push_idx].set(x) then gather emb[pull_idx].
// Last push (highest i) wins on duplicate push indices.
//
// Partition pipeline (best-of rounds 7-14):
//   bucket = key>>17 (512 buckets, 512KB emb window each)
//   K1: FUSED LDS-staged 512-bin scatter: push -> u64 (key|pos) runs;
//       pull -> int key runs + dest[j]=slot. LDS-atomic ranking,
//       bin-contiguous copy-out, ~512 global cursor atomics/block.
//   K2: WINDOW-GATHER (round-14): stream the bucket's 512KB emb window
//       through a 64KB LDS buffer in 8 chunks (reg-prefetch next chunk
//       during scan); serve ALL pulls stg[i] = win[key-lo] from LDS.
//       Replaces ~162MB random 64B-line gather @2.8TB/s with a 240MB
//       coalesced stream @~6.3TB/s. 2 WG/CU.
//   K3: PUSH-OVERRIDE: round-13 match minus emb: 16KB pull-bloom ->
//       filtered insert (4096-slot/32KB table, lf ~0.23) -> probe; only
//       matched pulls (~6.5%) overwrite stg[i] with x[winner pos].
//   K4: unpermute out[j] = staging[dest[j]].
// Winner = max push pos (order-free, atomicMax); K2->K3 kernel order makes
// the overwrite deterministic; each j reads its own staging slot.
// ---------------------------------------------------------------------------

typedef unsigned long long u64;
typedef unsigned u32;

#define NB     512              // buckets
#define BSHIFT 17               // bucket = key >> 17 (keys < 2^26)
#define BLK    256
#define MBLK   1024             // K2/K3 block: 16 waves
#define VPT    16
#define CHUNK  (BLK * VPT)      // 4096 items per scatter block
#define CAP    12288            // per-bucket run capacity (mean 7812, +50 sigma)
#define CPAD   16               // ints per cursor (64B line)
#define TSLOTS 4096             // K3 LDS hash slots (32KB), lf ~0.23
#define TMASK  (TSLOTS - 1)
#define BBITS  131072           // pull-bloom bits (2^17) = 16KB
#define BWORDS (BBITS / 32)
#define BMASK  (BBITS - 1)
#define WFL    16384            // window-chunk floats (64KB)
#define WCH    8                // chunks per 128K-key window

__device__ __forceinline__ u32 hkey(int key) { return (u32)key * 2654435761u; }

// ---- K1: fused LDS-binned scatter into 512 bucket runs (push + pull) ----
__global__ __launch_bounds__(BLK)
void scatter_kernel(const int* __restrict__ push_idx, int n_push, int gp,
                    const int* __restrict__ pull_idx, int n_pull,
                    int* __restrict__ cur_push, int* __restrict__ cur_pull,
                    u64* __restrict__ push_runs,
                    int* __restrict__ pull_keys, int* __restrict__ dest) {
    const bool is_push = (int)blockIdx.x < gp;
    const int* __restrict__ idx = is_push ? push_idx : pull_idx;
    const int n   = is_push ? n_push : n_pull;
    const int cid = is_push ? blockIdx.x : blockIdx.x - gp;
    int* __restrict__ cursors = is_push ? cur_push : cur_pull;

    __shared__ u64 buf[CHUNK];          // 32KB
    __shared__ int cnt[NB];             // 2KB
    __shared__ int basel[NB];           // 2KB
    __shared__ int baseg[NB];           // 2KB
    __shared__ int scan[NB];            // 2KB
    int t = threadIdx.x;
    for (int b = t; b < NB; b += BLK) cnt[b] = 0;
    __syncthreads();

    int base = cid * CHUNK;
    int   key_r[VPT];
    short bin_r[VPT];                   // < 512
    short pos_r[VPT];                   // < 4096
    #pragma unroll
    for (int e = 0; e < VPT; ++e) {
        int i = base + e * BLK + t;     // coalesced index load
        if (i < n) {
            int key = idx[i];
            int b = key >> BSHIFT;
            key_r[e] = key;
            bin_r[e] = (short)b;
            pos_r[e] = (short)atomicAdd(&cnt[b], 1);   // LDS atomic (cheap)
        } else bin_r[e] = -1;
    }
    __syncthreads();

    // exclusive scan of cnt -> basel (Hillis-Steele, 2 elems/thread)
    scan[t] = cnt[t]; scan[t + BLK] = cnt[t + BLK];
    __syncthreads();
    for (int d = 1; d < NB; d <<= 1) {
        int a0 = (t       >= d) ? scan[t       - d] : 0;
        int a1 = (t + BLK >= d) ? scan[t + BLK - d] : 0;
        __syncthreads();
        scan[t] += a0; scan[t + BLK] += a1;
        __syncthreads();
    }
    basel[t]       = scan[t]       - cnt[t];
    basel[t + BLK] = scan[t + BLK] - cnt[t + BLK];
    __syncthreads();

    // reserve global run space: ~512 global atomics per block (not 4096)
    for (int b = t; b < NB; b += BLK)
        if (cnt[b] > 0) baseg[b] = atomicAdd(&cursors[b * CPAD], cnt[b]);

    // stage items into LDS, bin-grouped
    #pragma unroll
    for (int e = 0; e < VPT; ++e) {
        if (bin_r[e] >= 0) {
            int i = base + e * BLK + t;
            buf[basel[bin_r[e]] + pos_r[e]] =
                ((u64)(u32)key_r[e] << 32) | (u32)i;    // key | original index
        }
    }
    __syncthreads();

    // copy out: consecutive threads -> consecutive buf slots -> bin-contiguous
    int total = scan[NB - 1];
    for (int q = t; q < total; q += BLK) {
        u64 packed = buf[q];
        int key = (int)(packed >> 32);
        int b = key >> BSHIFT;
        int r = baseg[b] + (q - basel[b]);
        if (r < CAP) {                                  // overflow guard (P~0)
            int gpos = b * CAP + r;
            if (is_push) {
                push_runs[gpos] = packed;               // key | push pos
            } else {
                pull_keys[gpos] = key;
                dest[(u32)packed] = gpos;               // dest[j] = staging slot
            }
        }
    }
}

// ---- K2: stream emb window through LDS, serve all pulls ----
__global__ __launch_bounds__(MBLK)
void window_gather_kernel(const int* __restrict__ pull_keys,
                          const int* __restrict__ cur_pull,
                          const float* __restrict__ emb, int num_emb,
                          float* __restrict__ staging) {
    __shared__ float win[WFL];          // 64KB -> 2 WG/CU
    int b = blockIdx.x;
    int nl = cur_pull[b * CPAD]; nl = nl < CAP ? nl : CAP;
    if (nl == 0) return;                // uniform (empty high buckets)
    const int* lkeys = pull_keys + (size_t)b * CAP;
    float* stg = staging + (size_t)b * CAP;
    const int t = threadIdx.x;
    const int nf4 = num_emb >> 2;
    const int winbase4 = (b << BSHIFT) >> 2;   // float4 idx of window start
    const float4* emb4 = (const float4*)emb;

    float4 pf[4];                       // 64B/thread prefetch regs
    #pragma unroll
    for (int k = 0; k < 4; ++k) {
        int f4 = winbase4 + k * MBLK + t;
        pf[k] = (f4 < nf4) ? emb4[f4] : make_float4(0.f, 0.f, 0.f, 0.f);
    }
    for (int c = 0; c < WCH; ++c) {
        __syncthreads();                // previous scan done (buffer free)
        #pragma unroll
        for (int k = 0; k < 4; ++k)
            ((float4*)win)[k * MBLK + t] = pf[k];
        __syncthreads();                // window chunk ready
        if (c + 1 < WCH) {              // prefetch next chunk; overlaps scan
            #pragma unroll
            for (int k = 0; k < 4; ++k) {
                int f4 = winbase4 + (c + 1) * (WFL / 4) + k * MBLK + t;
                pf[k] = (f4 < nf4) ? emb4[f4] : make_float4(0.f, 0.f, 0.f, 0.f);
            }
        }
        int lo = (b << BSHIFT) + c * WFL;
        for (int i = t * 4; i + 4 <= nl; i += MBLK * 4) {
            int4 kk = *(const int4*)(lkeys + i);
            int d0 = kk.x - lo, d1 = kk.y - lo, d2 = kk.z - lo, d3 = kk.w - lo;
            if ((u32)d0 < (u32)WFL) stg[i]     = win[d0];
            if ((u32)d1 < (u32)WFL) stg[i + 1] = win[d1];
            if ((u32)d2 < (u32)WFL) stg[i + 2] = win[d2];
            if ((u32)d3 < (u32)WFL) stg[i + 3] = win[d3];
        }
        int tail = nl & ~3;
        for (int i = tail + t; i < nl; i += MBLK) {
            int d = lkeys[i] - lo;
            if ((u32)d < (u32)WFL) stg[i] = win[d];
        }
    }
}

// ---- K3: pull-bloom-filtered push table; overwrite matched pulls with x ----
__global__ __launch_bounds__(MBLK)
void push_override_kernel(const u64* __restrict__ push_runs,
                          const int* __restrict__ pull_keys,
                          const int* __restrict__ cur_push,
                          const int* __restrict__ cur_pull,
                          const float* __restrict__ x,
                          float* __restrict__ staging) {
    __shared__ u32 bloom[BWORDS];   // 16KB: pulled-key bloom
    __shared__ u64 tbl[TSLOTS];     // 32KB: filtered push table (lf ~0.23)
    int b = blockIdx.x;
    int np = cur_push[b * CPAD]; np = np < CAP ? np : CAP;
    int nl = cur_pull[b * CPAD]; nl = nl < CAP ? nl : CAP;
    if (np == 0 || nl == 0) return;     // uniform
    for (int i = threadIdx.x; i < BWORDS; i += MBLK) bloom[i] = 0u;
    for (int i = threadIdx.x; i < TSLOTS; i += MBLK) tbl[i] = 0ull;
    __syncthreads();

    // p1: bloom of this bucket's pull keys
    const int* lkeys = pull_keys + (size_t)b * CAP;
    for (int i = threadIdx.x; i < nl; i += MBLK) {
        u32 h = hkey(lkeys[i]);
        atomicOr(&bloom[(h & BMASK) >> 5], 1u << (h & 31));
    }
    __syncthreads();

    // p2: insert only pushes whose key might be pulled (~12%)
    const u64* prun = push_runs + (size_t)b * CAP;
    for (int i = threadIdx.x; i < np; i += MBLK) {
        u64 packed = prun[i];
        int key = (int)(packed >> 32);
        u32 h = hkey(key);
        if (!((bloom[(h & BMASK) >> 5] >> (h & 31)) & 1u)) continue;
        u32 key1 = (u32)key + 1u;
        u64 want = ((u64)key1 << 32) | ((u32)packed + 1u);   // (key+1)|(pos+1)
        u32 s = (h >> 20) & TMASK;
        for (;;) {
            u64 prev = atomicCAS(&tbl[s], 0ull, want);
            if (prev == 0ull) break;                          // claimed
            if ((prev >> 32) == key1) { atomicMax(&tbl[s], want); break; }
            s = (s + 1) & TMASK;
        }
    }
    __syncthreads();

    // p3: probe pulls; only matched (~6.5%) overwrite staging with x[pos]
    float* stg = staging + (size_t)b * CAP;
    for (int i = threadIdx.x * 4; i + 4 <= nl; i += MBLK * 4) {
        int4 kk = *(const int4*)(lkeys + i);
        int k[4] = {kk.x, kk.y, kk.z, kk.w};
        u32 h[4]; u64 tv[4];
        #pragma unroll
        for (int e = 0; e < 4; ++e) h[e] = hkey(k[e]);
        #pragma unroll
        for (int e = 0; e < 4; ++e) tv[e] = tbl[(h[e] >> 20) & TMASK];
        #pragma unroll
        for (int e = 0; e < 4; ++e) {
            u64 cur = tv[e];
            u32 key1 = (u32)k[e] + 1u;
            u32 s = (h[e] >> 20) & TMASK;
            while (cur != 0ull) {
                if ((cur >> 32) == key1) { stg[i + e] = x[(u32)cur - 1u]; break; }
                s = (s + 1) & TMASK;
                cur = tbl[s];
            }
        }
    }
    int tail = nl & ~3;
    for (int i = tail + threadIdx.x; i < nl; i += MBLK) {
        int key = lkeys[i];
        u32 h = hkey(key);
        u32 key1 = (u32)key + 1u;
        u32 s = (h >> 20) & TMASK;
        for (;;) {
            u64 cur = tbl[s];
            if (cur == 0ull) break;
            if ((cur >> 32) == key1) { stg[i] = x[(u32)cur - 1u]; break; }
            s = (s + 1) & TMASK;
        }
    }
}

// ---- K4: unpermute (coalesced dest read, L3 staging gather, coalesced out) ----
__global__ __launch_bounds__(BLK)
void unpermute_kernel(const int* __restrict__ dest,
                      const float* __restrict__ staging,
                      float* __restrict__ out, int n) {
    int j0 = (blockIdx.x * BLK + threadIdx.x) * 4;
    if (j0 + 4 <= n) {
        int4 d = *(const int4*)(dest + j0);
        *(float4*)(out + j0) =
            make_float4(staging[d.x], staging[d.y], staging[d.z], staging[d.w]);
    } else {
        for (int j = j0; j < n; ++j) out[j] = staging[dest[j]];
    }
}

extern "C" void kernel_launch(void* const* d_in, const int* in_sizes, int n_in,
                              void* d_out, int out_size, void* d_ws, size_t ws_size,
                              hipStream_t stream) {
    const float* emb      = (const float*)d_in[0];
    const float* x        = (const float*)d_in[1];
    const int*   push_idx = (const int*)d_in[2];
    const int*   pull_idx = (const int*)d_in[3];
    float* out = (float*)d_out;

    const int num_emb = in_sizes[0];
    const int n_push  = in_sizes[2];
    const int n_pull  = in_sizes[3];

    // ws layout: [cur_push][cur_pull] (zeroed) [push_runs][pull_keys][staging][dest]
    char* p = (char*)d_ws;
    int* cur_push = (int*)p;                  p += (size_t)NB * CPAD * 4;
    int* cur_pull = (int*)p;                  p += (size_t)NB * CPAD * 4;
    size_t zero_bytes = (size_t)(p - (char*)d_ws);
    u64*   push_runs = (u64*)p;               p += (size_t)NB * CAP * 8;
    int*   pull_keys = (int*)p;               p += (size_t)NB * CAP * 4;
    float* staging   = (float*)p;             p += (size_t)NB * CAP * 4;
    int*   dest      = (int*)p;               p += (size_t)n_pull * 4;

    hipMemsetAsync(d_ws, 0, zero_bytes, stream);   // 64KB only

    int gp = (n_push + CHUNK - 1) / CHUNK;
    int gl = (n_pull + CHUNK - 1) / CHUNK;
    scatter_kernel<<<gp + gl, BLK, 0, stream>>>(
        push_idx, n_push, gp, pull_idx, n_pull,
        cur_push, cur_pull, push_runs, pull_keys, dest);
    window_gather_kernel<<<NB, MBLK, 0, stream>>>(pull_keys, cur_pull,
                                                  emb, num_emb, staging);
    push_override_kernel<<<NB, MBLK, 0, stream>>>(push_runs, pull_keys,
                                                  cur_push, cur_pull, x, staging);
    unpermute_kernel<<<(n_pull + BLK * 4 - 1) / (BLK * 4), BLK, 0, stream>>>(
        dest, staging, out, n_pull);
}

// Round 15
// 184.409 us; speedup vs baseline: 1.3072x; 1.3072x over previous
//
#include <hip/hip_runtime.h>
#include <stdint.h>

// ---------------------------------------------------------------------------
// HistoryEmbTable: emb.at[push_idx].set(x) then gather emb[pull_idx].
// Last push (highest i) wins on duplicate push indices.
//
// Partition pipeline (best-of rounds 7-15; round-14 window-streaming REVERTED:
// re-scan + sparse writes + 240MB-vs-162MB made it 31us slower than gather):
//   bucket = key>>17 (512 buckets, 512KB emb window each)
//   K1: FUSED LDS-staged 512-bin scatter. Round-15: BLK 256->512, VPT 16->8
//       (CHUNK stays 4096, LDS stays 40KB) -> 4 WG/CU = 32 waves/CU (HW max,
//       was 16) and the bin scan is 1 elem/thread. push -> u64 (key|pos)
//       runs; pull -> int key runs + dest[j]=slot. ~512 cursor atomics/block.
//   K2: match (round-13 form, VERBATIM — VGPR 52 <= 64 keeps 2 WG/CU at
//       MBLK=1024; MB=8 would halve occupancy, round-9 lesson):
//         p1: 16KB bloom of this bucket's pull keys;
//         p2: insert pushes passing the bloom (~12%) into 4096-slot (32KB)
//             table, lf ~0.23 -> first probe read conclusive-empty 77%;
//         p3: batch-4 probe, emb[key] in flight, coalesced float4 staging.
//   K3: unpermute out[j] = staging[dest[j]].
// Winner = max push pos (order-free, atomicMax); each j reads its own staging
// slot -> deterministic output despite nondeterministic scatter order.
// ---------------------------------------------------------------------------

typedef unsigned long long u64;
typedef unsigned u32;

#define NB     512              // buckets
#define BSHIFT 17               // bucket = key >> 17 (keys < 2^26)
#define SBLK   512              // scatter block (round-15: was 256)
#define BLK    256              // unpermute block
#define MBLK   1024             // match block: 16 waves; 2 WG/CU via 48KB LDS
#define MB     4                // match batch (items/thread/iter)
#define VPT    8                // scatter items/thread (round-15: was 16)
#define CHUNK  (SBLK * VPT)     // 4096 items per scatter block
#define CAP    12288            // per-bucket run capacity (mean 7812, +50 sigma)
#define CPAD   16               // ints per cursor (64B line)
#define TSLOTS 4096             // LDS hash slots (32KB), lf ~0.23
#define TMASK  (TSLOTS - 1)
#define BBITS  131072           // pull-bloom bits (2^17) = 16KB
#define BWORDS (BBITS / 32)
#define BMASK  (BBITS - 1)

__device__ __forceinline__ u32 hkey(int key) { return (u32)key * 2654435761u; }

// ---- K1: fused LDS-binned scatter into 512 bucket runs (push + pull) ----
__global__ __launch_bounds__(SBLK)
void scatter_kernel(const int* __restrict__ push_idx, int n_push, int gp,
                    const int* __restrict__ pull_idx, int n_pull,
                    int* __restrict__ cur_push, int* __restrict__ cur_pull,
                    u64* __restrict__ push_runs,
                    int* __restrict__ pull_keys, int* __restrict__ dest) {
    const bool is_push = (int)blockIdx.x < gp;
    const int* __restrict__ idx = is_push ? push_idx : pull_idx;
    const int n   = is_push ? n_push : n_pull;
    const int cid = is_push ? blockIdx.x : blockIdx.x - gp;
    int* __restrict__ cursors = is_push ? cur_push : cur_pull;

    __shared__ u64 buf[CHUNK];          // 32KB
    __shared__ int cnt[NB];             // 2KB
    __shared__ int basel[NB];           // 2KB
    __shared__ int baseg[NB];           // 2KB
    __shared__ int scan[NB];            // 2KB   (total 40KB -> 4 WG/CU)
    int t = threadIdx.x;
    cnt[t] = 0;                         // SBLK == NB
    __syncthreads();

    int base = cid * CHUNK;
    int   key_r[VPT];
    short bin_r[VPT];                   // < 512
    short pos_r[VPT];                   // < 4096
    #pragma unroll
    for (int e = 0; e < VPT; ++e) {
        int i = base + e * SBLK + t;    // coalesced index load
        if (i < n) {
            int key = idx[i];
            int b = key >> BSHIFT;
            key_r[e] = key;
            bin_r[e] = (short)b;
            pos_r[e] = (short)atomicAdd(&cnt[b], 1);   // LDS atomic (cheap)
        } else bin_r[e] = -1;
    }
    __syncthreads();

    // exclusive scan of cnt -> basel (Hillis-Steele, 1 elem/thread)
    int c = cnt[t];
    scan[t] = c;
    __syncthreads();
    for (int d = 1; d < NB; d <<= 1) {
        int a = (t >= d) ? scan[t - d] : 0;
        __syncthreads();
        scan[t] += a;
        __syncthreads();
    }
    basel[t] = scan[t] - c;
    // reserve global run space: 512 global atomics per block (not 4096)
    if (c > 0) baseg[t] = atomicAdd(&cursors[t * CPAD], c);
    __syncthreads();

    // stage items into LDS, bin-grouped
    #pragma unroll
    for (int e = 0; e < VPT; ++e) {
        if (bin_r[e] >= 0) {
            int i = base + e * SBLK + t;
            buf[basel[bin_r[e]] + pos_r[e]] =
                ((u64)(u32)key_r[e] << 32) | (u32)i;    // key | original index
        }
    }
    __syncthreads();

    // copy out: consecutive threads -> consecutive buf slots -> bin-contiguous
    int total = scan[NB - 1];
    for (int q = t; q < total; q += SBLK) {
        u64 packed = buf[q];
        int key = (int)(packed >> 32);
        int b = key >> BSHIFT;
        int r = baseg[b] + (q - basel[b]);
        if (r < CAP) {                                  // overflow guard (P~0)
            int gpos = b * CAP + r;
            if (is_push) {
                push_runs[gpos] = packed;               // key | push pos
            } else {
                pull_keys[gpos] = key;
                dest[(u32)packed] = gpos;               // dest[j] = staging slot
            }
        }
    }
}

// ---- K2: per-bucket pull-bloom-filtered LDS match -> coalesced staging ----
__global__ __launch_bounds__(MBLK)
void match_kernel(const u64* __restrict__ push_runs,
                  const int* __restrict__ pull_keys,
                  const int* __restrict__ cur_push,
                  const int* __restrict__ cur_pull,
                  const float* __restrict__ x,
                  const float* __restrict__ emb,
                  float* __restrict__ staging) {
    __shared__ u32 bloom[BWORDS];   // 16KB: pulled-key bloom
    __shared__ u64 tbl[TSLOTS];     // 32KB: filtered push table (lf ~0.23)
    int b = blockIdx.x;
    int np = cur_push[b * CPAD]; np = np < CAP ? np : CAP;
    int nl = cur_pull[b * CPAD]; nl = nl < CAP ? nl : CAP;
    for (int i = threadIdx.x; i < BWORDS; i += MBLK) bloom[i] = 0u;
    for (int i = threadIdx.x; i < TSLOTS; i += MBLK) tbl[i] = 0ull;
    __syncthreads();

    // phase 1: bloom of this bucket's pull keys
    const int* lkeys = pull_keys + (size_t)b * CAP;
    for (int i = threadIdx.x; i < nl; i += MBLK) {
        u32 h = hkey(lkeys[i]);
        atomicOr(&bloom[(h & BMASK) >> 5], 1u << (h & 31));
    }
    __syncthreads();

    // phase 2: insert only pushes whose key might be pulled (~12%)
    const u64* prun = push_runs + (size_t)b * CAP;
    for (int i = threadIdx.x; i < np; i += MBLK) {
        u64 packed = prun[i];
        int key = (int)(packed >> 32);
        u32 h = hkey(key);
        if (!((bloom[(h & BMASK) >> 5] >> (h & 31)) & 1u)) continue;
        u32 key1 = (u32)key + 1u;
        u64 want = ((u64)key1 << 32) | ((u32)packed + 1u);   // (key+1)|(pos+1)
        u32 s = (h >> 20) & TMASK;
        for (;;) {
            u64 prev = atomicCAS(&tbl[s], 0ull, want);
            if (prev == 0ull) break;                          // claimed
            if ((prev >> 32) == key1) { atomicMax(&tbl[s], want); break; }
            s = (s + 1) & TMASK;
        }
    }
    __syncthreads();

    // phase 3: probe pulls, batch-4: emb loads in flight; first table read is
    // conclusive-empty ~77%; coalesced float4 staging store.
    float* stg = staging + (size_t)b * CAP;
    const int STRIDE = MBLK * MB;                 // 4096
    for (int i = threadIdx.x * MB; i + MB <= nl; i += STRIDE) {
        int4 kk = *(const int4*)(lkeys + i);
        int k[MB] = {kk.x, kk.y, kk.z, kk.w};
        float g[MB];
        #pragma unroll
        for (int e = 0; e < MB; ++e) g[e] = emb[k[e]];        // 4 in flight
        u32 h[MB]; u64 tv[MB];
        #pragma unroll
        for (int e = 0; e < MB; ++e) h[e] = hkey(k[e]);
        #pragma unroll
        for (int e = 0; e < MB; ++e) tv[e] = tbl[(h[e] >> 20) & TMASK];
        float r[MB];
        #pragma unroll
        for (int e = 0; e < MB; ++e) {
            float v = g[e];
            u64 cur = tv[e];
            u32 key1 = (u32)k[e] + 1u;
            u32 s = (h[e] >> 20) & TMASK;
            while (cur != 0ull) {                             // walk (rare)
                if ((cur >> 32) == key1) { v = x[(u32)cur - 1u]; break; }
                s = (s + 1) & TMASK;
                cur = tbl[s];
            }
            r[e] = v;
        }
        *(float4*)(stg + i) = make_float4(r[0], r[1], r[2], r[3]);
    }
    // tail (< MB items at the end)
    int tail = (nl / MB) * MB;
    for (int i = tail + threadIdx.x; i < nl; i += MBLK) {
        int key = lkeys[i];
        float v = emb[key];
        u32 h = hkey(key);
        u32 key1 = (u32)key + 1u;
        u32 s = (h >> 20) & TMASK;
        for (;;) {
            u64 cur = tbl[s];
            if (cur == 0ull) break;
            if ((cur >> 32) == key1) { v = x[(u32)cur - 1u]; break; }
            s = (s + 1) & TMASK;
        }
        stg[i] = v;
    }
}

// ---- K3: unpermute (coalesced dest read, L3 staging gather, coalesced out) ----
__global__ __launch_bounds__(BLK)
void unpermute_kernel(const int* __restrict__ dest,
                      const float* __restrict__ staging,
                      float* __restrict__ out, int n) {
    int j0 = (blockIdx.x * BLK + threadIdx.x) * 4;
    if (j0 + 4 <= n) {
        int4 d = *(const int4*)(dest + j0);
        *(float4*)(out + j0) =
            make_float4(staging[d.x], staging[d.y], staging[d.z], staging[d.w]);
    } else {
        for (int j = j0; j < n; ++j) out[j] = staging[dest[j]];
    }
}

extern "C" void kernel_launch(void* const* d_in, const int* in_sizes, int n_in,
                              void* d_out, int out_size, void* d_ws, size_t ws_size,
                              hipStream_t stream) {
    const float* emb      = (const float*)d_in[0];
    const float* x        = (const float*)d_in[1];
    const int*   push_idx = (const int*)d_in[2];
    const int*   pull_idx = (const int*)d_in[3];
    float* out = (float*)d_out;

    const int n_push = in_sizes[2];
    const int n_pull = in_sizes[3];

    // ws layout: [cur_push][cur_pull] (zeroed) [push_runs][pull_keys][staging][dest]
    char* p = (char*)d_ws;
    int* cur_push = (int*)p;                  p += (size_t)NB * CPAD * 4;
    int* cur_pull = (int*)p;                  p += (size_t)NB * CPAD * 4;
    size_t zero_bytes = (size_t)(p - (char*)d_ws);
    u64*   push_runs = (u64*)p;               p += (size_t)NB * CAP * 8;
    int*   pull_keys = (int*)p;               p += (size_t)NB * CAP * 4;
    float* staging   = (float*)p;             p += (size_t)NB * CAP * 4;
    int*   dest      = (int*)p;               p += (size_t)n_pull * 4;

    hipMemsetAsync(d_ws, 0, zero_bytes, stream);   // 64KB only

    int gp = (n_push + CHUNK - 1) / CHUNK;
    int gl = (n_pull + CHUNK - 1) / CHUNK;
    scatter_kernel<<<gp + gl, SBLK, 0, stream>>>(
        push_idx, n_push, gp, pull_idx, n_pull,
        cur_push, cur_pull, push_runs, pull_keys, dest);
    match_kernel<<<NB, MBLK, 0, stream>>>(push_runs, pull_keys,
                                          cur_push, cur_pull, x, emb, staging);
    unpermute_kernel<<<(n_pull + BLK * 4 - 1) / (BLK * 4), BLK, 0, stream>>>(
        dest, staging, out, n_pull);
}

// Round 16
// 169.349 us; speedup vs baseline: 1.4235x; 1.0889x over previous
//
#include <hip/hip_runtime.h>
#include <stdint.h>

// ---------------------------------------------------------------------------
// HistoryEmbTable: emb.at[push_idx].set(x) then gather emb[pull_idx].
// Last push (highest i) wins on duplicate push indices.
//
// Partition pipeline (best-of rounds 7-16):
//   bucket = key>>17 (512 buckets, 512KB emb window each)
//   K1: FUSED LDS-staged 512-bin scatter. Round-16: SBLK 512->1024, CHUNK
//       4096->8192 (LDS 72KB -> still 2 WG/CU = 32 waves/CU max); average
//       bin-contiguous copy-out segment doubles to 16 items (128B push/
//       64B pull) -- round-15 measured scatter ~45us vs ~15us stream floor,
//       gap = sub-line write fragmentation. push -> u64 (key|pos) runs;
//       pull -> int key runs + dest[j]=slot. 512 cursor atomics/block.
//   K2: match (round-13 form, VERBATIM core — VGPR 52 <= 64 keeps 2 WG/CU
//       at MBLK=1024 = 32 waves/CU; round-9: deeper batch halves occupancy):
//         p1: 16KB bloom of this bucket's pull keys (int4 key loads);
//         p2: insert pushes passing the bloom (~12%) into 4096-slot (32KB)
//             table, lf ~0.23 -> first probe read conclusive-empty 77%;
//         p3: batch-4 probe, emb[key] in flight, coalesced float4 staging.
//   K3: unpermute out[j] = staging[dest[j]].
// Winner = max push pos (order-free, atomicMax); each j reads its own staging
// slot -> deterministic output despite nondeterministic scatter order.
// ---------------------------------------------------------------------------

typedef unsigned long long u64;
typedef unsigned u32;

#define NB     512              // buckets
#define BSHIFT 17               // bucket = key >> 17 (keys < 2^26)
#define SBLK   1024             // scatter block (round-16: was 512)
#define BLK    256              // unpermute block
#define MBLK   1024             // match block: 16 waves; 2 WG/CU via 48KB LDS
#define MB     4                // match batch (items/thread/iter)
#define VPT    8                // scatter items/thread
#define CHUNK  (SBLK * VPT)     // 8192 items per scatter block
#define CAP    12288            // per-bucket run capacity (mean 7812, +50 sigma)
#define CPAD   16               // ints per cursor (64B line)
#define TSLOTS 4096             // LDS hash slots (32KB), lf ~0.23
#define TMASK  (TSLOTS - 1)
#define BBITS  131072           // pull-bloom bits (2^17) = 16KB
#define BWORDS (BBITS / 32)
#define BMASK  (BBITS - 1)

__device__ __forceinline__ u32 hkey(int key) { return (u32)key * 2654435761u; }

// ---- K1: fused LDS-binned scatter into 512 bucket runs (push + pull) ----
__global__ __launch_bounds__(SBLK)
void scatter_kernel(const int* __restrict__ push_idx, int n_push, int gp,
                    const int* __restrict__ pull_idx, int n_pull,
                    int* __restrict__ cur_push, int* __restrict__ cur_pull,
                    u64* __restrict__ push_runs,
                    int* __restrict__ pull_keys, int* __restrict__ dest) {
    const bool is_push = (int)blockIdx.x < gp;
    const int* __restrict__ idx = is_push ? push_idx : pull_idx;
    const int n   = is_push ? n_push : n_pull;
    const int cid = is_push ? blockIdx.x : blockIdx.x - gp;
    int* __restrict__ cursors = is_push ? cur_push : cur_pull;

    __shared__ u64 buf[CHUNK];          // 64KB
    __shared__ int cnt[NB];             // 2KB
    __shared__ int basel[NB];           // 2KB
    __shared__ int baseg[NB];           // 2KB
    __shared__ int scan[NB];            // 2KB   (total 72KB -> 2 WG/CU)
    int t = threadIdx.x;
    if (t < NB) cnt[t] = 0;
    __syncthreads();

    int base = cid * CHUNK;
    int   key_r[VPT];
    short bin_r[VPT];                   // < 512
    short pos_r[VPT];                   // < 8192
    #pragma unroll
    for (int e = 0; e < VPT; ++e) {
        int i = base + e * SBLK + t;    // coalesced index load
        if (i < n) {
            int key = idx[i];
            int b = key >> BSHIFT;
            key_r[e] = key;
            bin_r[e] = (short)b;
            pos_r[e] = (short)atomicAdd(&cnt[b], 1);   // LDS atomic (cheap)
        } else bin_r[e] = -1;
    }
    __syncthreads();

    // exclusive scan of cnt -> basel (Hillis-Steele, guarded; barriers uniform)
    int c = (t < NB) ? cnt[t] : 0;
    if (t < NB) scan[t] = c;
    __syncthreads();
    for (int d = 1; d < NB; d <<= 1) {
        int a = (t >= d && t < NB) ? scan[t - d] : 0;
        __syncthreads();
        if (t < NB) scan[t] += a;
        __syncthreads();
    }
    if (t < NB) {
        basel[t] = scan[t] - c;
        // reserve global run space: 512 global atomics per block (not 8192)
        if (c > 0) baseg[t] = atomicAdd(&cursors[t * CPAD], c);
    }
    __syncthreads();

    // stage items into LDS, bin-grouped
    #pragma unroll
    for (int e = 0; e < VPT; ++e) {
        if (bin_r[e] >= 0) {
            int i = base + e * SBLK + t;
            buf[basel[bin_r[e]] + pos_r[e]] =
                ((u64)(u32)key_r[e] << 32) | (u32)i;    // key | original index
        }
    }
    __syncthreads();

    // copy out: consecutive threads -> consecutive buf slots -> bin-contiguous
    int total = scan[NB - 1];
    for (int q = t; q < total; q += SBLK) {
        u64 packed = buf[q];
        int key = (int)(packed >> 32);
        int b = key >> BSHIFT;
        int r = baseg[b] + (q - basel[b]);
        if (r < CAP) {                                  // overflow guard (P~0)
            int gpos = b * CAP + r;
            if (is_push) {
                push_runs[gpos] = packed;               // key | push pos
            } else {
                pull_keys[gpos] = key;
                dest[(u32)packed] = gpos;               // dest[j] = staging slot
            }
        }
    }
}

// ---- K2: per-bucket pull-bloom-filtered LDS match -> coalesced staging ----
__global__ __launch_bounds__(MBLK)
void match_kernel(const u64* __restrict__ push_runs,
                  const int* __restrict__ pull_keys,
                  const int* __restrict__ cur_push,
                  const int* __restrict__ cur_pull,
                  const float* __restrict__ x,
                  const float* __restrict__ emb,
                  float* __restrict__ staging) {
    __shared__ u32 bloom[BWORDS];   // 16KB: pulled-key bloom
    __shared__ u64 tbl[TSLOTS];     // 32KB: filtered push table (lf ~0.23)
    int b = blockIdx.x;
    int np = cur_push[b * CPAD]; np = np < CAP ? np : CAP;
    int nl = cur_pull[b * CPAD]; nl = nl < CAP ? nl : CAP;
    for (int i = threadIdx.x; i < BWORDS; i += MBLK) bloom[i] = 0u;
    for (int i = threadIdx.x; i < TSLOTS; i += MBLK) tbl[i] = 0ull;
    __syncthreads();

    // phase 1: bloom of this bucket's pull keys (int4 loads)
    const int* lkeys = pull_keys + (size_t)b * CAP;
    for (int i = threadIdx.x * 4; i + 4 <= nl; i += MBLK * 4) {
        int4 kk = *(const int4*)(lkeys + i);
        u32 h0 = hkey(kk.x), h1 = hkey(kk.y), h2 = hkey(kk.z), h3 = hkey(kk.w);
        atomicOr(&bloom[(h0 & BMASK) >> 5], 1u << (h0 & 31));
        atomicOr(&bloom[(h1 & BMASK) >> 5], 1u << (h1 & 31));
        atomicOr(&bloom[(h2 & BMASK) >> 5], 1u << (h2 & 31));
        atomicOr(&bloom[(h3 & BMASK) >> 5], 1u << (h3 & 31));
    }
    for (int i = (nl & ~3) + threadIdx.x; i < nl; i += MBLK) {
        u32 h = hkey(lkeys[i]);
        atomicOr(&bloom[(h & BMASK) >> 5], 1u << (h & 31));
    }
    __syncthreads();

    // phase 2: insert only pushes whose key might be pulled (~12%)
    const u64* prun = push_runs + (size_t)b * CAP;
    for (int i = threadIdx.x; i < np; i += MBLK) {
        u64 packed = prun[i];
        int key = (int)(packed >> 32);
        u32 h = hkey(key);
        if (!((bloom[(h & BMASK) >> 5] >> (h & 31)) & 1u)) continue;
        u32 key1 = (u32)key + 1u;
        u64 want = ((u64)key1 << 32) | ((u32)packed + 1u);   // (key+1)|(pos+1)
        u32 s = (h >> 20) & TMASK;
        for (;;) {
            u64 prev = atomicCAS(&tbl[s], 0ull, want);
            if (prev == 0ull) break;                          // claimed
            if ((prev >> 32) == key1) { atomicMax(&tbl[s], want); break; }
            s = (s + 1) & TMASK;
        }
    }
    __syncthreads();

    // phase 3: probe pulls, batch-4: emb loads in flight; first table read is
    // conclusive-empty ~77%; coalesced float4 staging store.
    float* stg = staging + (size_t)b * CAP;
    const int STRIDE = MBLK * MB;                 // 4096
    for (int i = threadIdx.x * MB; i + MB <= nl; i += STRIDE) {
        int4 kk = *(const int4*)(lkeys + i);
        int k[MB] = {kk.x, kk.y, kk.z, kk.w};
        float g[MB];
        #pragma unroll
        for (int e = 0; e < MB; ++e) g[e] = emb[k[e]];        // 4 in flight
        u32 h[MB]; u64 tv[MB];
        #pragma unroll
        for (int e = 0; e < MB; ++e) h[e] = hkey(k[e]);
        #pragma unroll
        for (int e = 0; e < MB; ++e) tv[e] = tbl[(h[e] >> 20) & TMASK];
        float r[MB];
        #pragma unroll
        for (int e = 0; e < MB; ++e) {
            float v = g[e];
            u64 cur = tv[e];
            u32 key1 = (u32)k[e] + 1u;
            u32 s = (h[e] >> 20) & TMASK;
            while (cur != 0ull) {                             // walk (rare)
                if ((cur >> 32) == key1) { v = x[(u32)cur - 1u]; break; }
                s = (s + 1) & TMASK;
                cur = tbl[s];
            }
            r[e] = v;
        }
        *(float4*)(stg + i) = make_float4(r[0], r[1], r[2], r[3]);
    }
    // tail (< MB items at the end)
    int tail = (nl / MB) * MB;
    for (int i = tail + threadIdx.x; i < nl; i += MBLK) {
        int key = lkeys[i];
        float v = emb[key];
        u32 h = hkey(key);
        u32 key1 = (u32)key + 1u;
        u32 s = (h >> 20) & TMASK;
        for (;;) {
            u64 cur = tbl[s];
            if (cur == 0ull) break;
            if ((cur >> 32) == key1) { v = x[(u32)cur - 1u]; break; }
            s = (s + 1) & TMASK;
        }
        stg[i] = v;
    }
}

// ---- K3: unpermute (coalesced dest read, L3 staging gather, coalesced out) ----
__global__ __launch_bounds__(BLK)
void unpermute_kernel(const int* __restrict__ dest,
                      const float* __restrict__ staging,
                      float* __restrict__ out, int n) {
    int j0 = (blockIdx.x * BLK + threadIdx.x) * 4;
    if (j0 + 4 <= n) {
        int4 d = *(const int4*)(dest + j0);
        *(float4*)(out + j0) =
            make_float4(staging[d.x], staging[d.y], staging[d.z], staging[d.w]);
    } else {
        for (int j = j0; j < n; ++j) out[j] = staging[dest[j]];
    }
}

extern "C" void kernel_launch(void* const* d_in, const int* in_sizes, int n_in,
                              void* d_out, int out_size, void* d_ws, size_t ws_size,
                              hipStream_t stream) {
    const float* emb      = (const float*)d_in[0];
    const float* x        = (const float*)d_in[1];
    const int*   push_idx = (const int*)d_in[2];
    const int*   pull_idx = (const int*)d_in[3];
    float* out = (float*)d_out;

    const int n_push = in_sizes[2];
    const int n_pull = in_sizes[3];

    // ws layout: [cur_push][cur_pull] (zeroed) [push_runs][pull_keys][staging][dest]
    char* p = (char*)d_ws;
    int* cur_push = (int*)p;                  p += (size_t)NB * CPAD * 4;
    int* cur_pull = (int*)p;                  p += (size_t)NB * CPAD * 4;
    size_t zero_bytes = (size_t)(p - (char*)d_ws);
    u64*   push_runs = (u64*)p;               p += (size_t)NB * CAP * 8;
    int*   pull_keys = (int*)p;               p += (size_t)NB * CAP * 4;
    float* staging   = (float*)p;             p += (size_t)NB * CAP * 4;
    int*   dest      = (int*)p;               p += (size_t)n_pull * 4;

    hipMemsetAsync(d_ws, 0, zero_bytes, stream);   // 64KB only

    int gp = (n_push + CHUNK - 1) / CHUNK;
    int gl = (n_pull + CHUNK - 1) / CHUNK;
    scatter_kernel<<<gp + gl, SBLK, 0, stream>>>(
        push_idx, n_push, gp, pull_idx, n_pull,
        cur_push, cur_pull, push_runs, pull_keys, dest);
    match_kernel<<<NB, MBLK, 0, stream>>>(push_runs, pull_keys,
                                          cur_push, cur_pull, x, emb, staging);
    unpermute_kernel<<<(n_pull + BLK * 4 - 1) / (BLK * 4), BLK, 0, stream>>>(
        dest, staging, out, n_pull);
}